// Round 11
// baseline (49.000 us; speedup 1.0000x reference)
//
#include <hip/hip_runtime.h>
#include <math.h>

#define P 7
#define PP (P * P)
#define C 256
#define H 64
#define W 64
#define S (H * W)
#define R_MAX 1024

#define NCP 25                // cell-pairs per roi (49 cells -> 25 pairs)
#define BMAX 10               // max bin extent: ceil(63/7)+1
#define HPAD 129              // reorder half-block LDS pad

// ---------------------------------------------------------------------------
// Transpose [N, C, S] -> [N, S, C], 64x64 tiles, float4 global on BOTH sides.
// Block (0,0,0) additionally computes the roi->slot permutation (stable
// counting sort by image id) -- runs concurrently, saving a dispatch.
// ---------------------------------------------------------------------------
#define TT 64
#define TPAD 65
__global__ __launch_bounds__(256) void transpose_bucket_kernel(
    const float* __restrict__ in, float* __restrict__ outT,
    const float* __restrict__ rois, int* __restrict__ perm, int R)
{
    __shared__ float tile[TT * TPAD];      // 16.6 KB
    const int b   = blockIdx.z;
    const int s0  = blockIdx.x * TT;
    const int c0  = blockIdx.y * TT;
    const int t   = threadIdx.x;
    const int r16 = t >> 4;                // 0..15
    const int m16 = (t & 15) * 4;          // 0,4,...,60

    #pragma unroll
    for (int k = 0; k < 4; ++k) {
        const int cl = r16 + 16 * k;
        const float4 v = *(const float4*)(in + (size_t)(b * C + c0 + cl) * S + s0 + m16);
        tile[cl * TPAD + m16 + 0] = v.x;
        tile[cl * TPAD + m16 + 1] = v.y;
        tile[cl * TPAD + m16 + 2] = v.z;
        tile[cl * TPAD + m16 + 3] = v.w;
    }
    __syncthreads();
    #pragma unroll
    for (int k = 0; k < 4; ++k) {
        const int sl = r16 + 16 * k;
        float4 v;
        v.x = tile[(m16 + 0) * TPAD + sl];
        v.y = tile[(m16 + 1) * TPAD + sl];
        v.z = tile[(m16 + 2) * TPAD + sl];
        v.w = tile[(m16 + 3) * TPAD + sl];
        *(float4*)(outT + (size_t)(b * S + s0 + sl) * C + c0 + m16) = v;
    }

    if (blockIdx.x == 0 && blockIdx.y == 0 && blockIdx.z == 0 && R > 0 && R <= R_MAX) {
        __shared__ int bimg[R_MAX];        // 4 KB
        for (int i = t; i < R; i += 256)
            bimg[i] = (int)rois[(size_t)i * 5];
        __syncthreads();
        for (int i = t; i < R; i += 256) {
            const int myb = bimg[i];
            int pos = 0;
            for (int k = 0; k < R; ++k) {
                const int bk = bimg[k];
                pos += (bk < myb) || (bk == myb && k < i);
            }
            perm[pos] = i;
        }
    }
}

// ---------------------------------------------------------------------------
// RoI max-pool: block = (rslot, cell-PAIR), 128 threads = 2 waves, wave=cell.
// Inner loop fully unrolled across bin width (<= BMAX, clamped duplicate
// loads are idempotent for max): all 20 row-pair loads issue before one
// vmcnt wait -> dependent chain <= 5 batches even for 10x10 bins.
// ---------------------------------------------------------------------------
__global__ __launch_bounds__(128) void roi_pool_cell_kernel(
    const float* __restrict__ ft,    // [N, H, W, C]
    const float* __restrict__ rois,
    const int*   __restrict__ perm,
    float* __restrict__ ws2)         // [R, PP, C]
{
    const int l   = blockIdx.x;
    const int nwg = gridDim.x;            // R * NCP
    const int work  = ((nwg & 7) == 0) ? ((l & 7) * (nwg >> 3) + (l >> 3)) : l;
    const int rslot = work / NCP;
    const int cp    = work % NCP;
    const int cell  = 2 * cp + (threadIdx.x >> 6);
    const int q     = threadIdx.x & 63;   // channel quad 0..63

    if (cell >= PP) return;               // wave-uniform tail exit

    const int r = perm[rslot];
    const float* roi = rois + (size_t)r * 5;
    const int b = (int)roi[0];
    // jnp.round is half-to-even; rintf matches (RNE); *2^-5 scale is exact.
    int x0 = (int)rintf(roi[1] * 0.03125f);
    int y0 = (int)rintf(roi[2] * 0.03125f);
    int x1 = (int)rintf(roi[3] * 0.03125f);
    int y1 = (int)rintf(roi[4] * 0.03125f);
    x0 = min(max(x0, 0), W - 1);
    y0 = min(max(y0, 0), H - 1);
    x1 = min(max(x1, 0), W - 1);
    y1 = min(max(y1, 0), H - 1);

    float4* o = (float4*)(ws2 + ((size_t)rslot * PP + cell) * C) + q;

    if (!((x0 < x1) && (y0 < y1))) {
        *o = make_float4(0.0f, 0.0f, 0.0f, 0.0f);
        return;
    }

    const int Lh = x1 - x0;  // x-range bins the H axis (reference quirk)
    const int Lw = y1 - y0;  // y-range bins the W axis
    const int i  = cell / P;
    const int j  = cell - P * i;

    const int hs = x0 + (i * Lh) / P;
    const int he = x0 + ((i + 1) * Lh + (P - 1)) / P;
    const int ws = y0 + (j * Lw) / P;
    const int we = y0 + ((j + 1) * Lw + (P - 1)) / P;
    const int bh = he - hs;               // 1..BMAX
    const int bw = we - ws;               // 1..BMAX

    const float* base = ft + (((size_t)b * H + hs) * W + ws) * C + q * 4;

    float mx = -INFINITY, my = -INFINITY, mz = -INFINITY, mw = -INFINITY;
    for (int h = 0; h < bh; h += 2) {
        const int h2 = min(h + 1, bh - 1);        // clamp: dup row no-op for max
        const float* r0 = base + (size_t)h  * (W * C);
        const float* r1 = base + (size_t)h2 * (W * C);
        float4 v0[BMAX], v1[BMAX];
        #pragma unroll
        for (int k = 0; k < BMAX; ++k) {          // clamp: dup col no-op, L1 hit
            const int w = min(k, bw - 1);
            v0[k] = *(const float4*)(r0 + (size_t)w * C);
            v1[k] = *(const float4*)(r1 + (size_t)w * C);
        }
        #pragma unroll
        for (int k = 0; k < BMAX; ++k) {
            mx = fmaxf(mx, fmaxf(v0[k].x, v1[k].x));
            my = fmaxf(my, fmaxf(v0[k].y, v1[k].y));
            mz = fmaxf(mz, fmaxf(v0[k].z, v1[k].z));
            mw = fmaxf(mw, fmaxf(v0[k].w, v1[k].w));
        }
    }

    *o = make_float4(mx, my, mz, mw);
}

// ---------------------------------------------------------------------------
// Reorder ws2[rslot, cell, C] -> out[r, C, cell]. Block = (rslot, 128-ch
// half): LDS 25.3 KB (6 blocks/CU capacity), 2R blocks. Both sides coalesced;
// out written as full-line float4 stores.
// ---------------------------------------------------------------------------
__global__ __launch_bounds__(256) void reorder_kernel(
    const float* __restrict__ ws2,
    const int*   __restrict__ perm,
    float* __restrict__ out)         // [R, C, PP]
{
    __shared__ float lds[PP * HPAD];   // 49*129*4 = 25.3 KB
    const int l   = blockIdx.x;
    const int nwg = gridDim.x;         // 2R
    const int work  = ((nwg & 7) == 0) ? ((l & 7) * (nwg >> 3) + (l >> 3)) : l;
    const int rslot = work >> 1;
    const int half  = work & 1;
    const int r   = perm[rslot];
    const int t   = threadIdx.x;
    const int c0  = half * (C / 2);

    const float* src = ws2 + ((size_t)rslot * PP) * C + c0;
    {
        const int cell2 = t >> 7;      // 0/1
        const int c     = t & 127;
        #pragma unroll
        for (int base = 0; base < PP - 1; base += 2)
            lds[(base + cell2) * HPAD + c] = src[(size_t)(base + cell2) * C + c];
        if (t < 128)
            lds[(PP - 1) * HPAD + t] = src[(size_t)(PP - 1) * C + t];
    }

    __syncthreads();

    float* dst = out + ((size_t)r * C + c0) * PP;
    const int nq = ((C / 2) * PP) / 4;   // 1568 float4s
    #pragma unroll
    for (int k = 0; k < 7; ++k) {
        const int qf = t + 256 * k;
        if (qf < nq) {
            float v[4];
            #pragma unroll
            for (int m = 0; m < 4; ++m) {
                const int idx  = 4 * qf + m;
                const int c    = idx / PP;
                const int cell = idx - PP * c;
                v[m] = lds[cell * HPAD + c];
            }
            *(float4*)(dst + 4 * qf) = make_float4(v[0], v[1], v[2], v[3]);
        }
    }
}

// ---------------------------------------------------------------------------
// Fallback tier 1: pool with direct strided out writes (no perm/ws2 needed)
// ---------------------------------------------------------------------------
__global__ __launch_bounds__(64) void roi_pool_cell_direct_kernel(
    const float* __restrict__ ft, const float* __restrict__ rois,
    float* __restrict__ out)
{
    const int bid = blockIdx.x;
    const int r   = bid / PP;
    const int rem = bid % PP;
    const int i   = rem / P;
    const int j   = rem % P;
    const int c4  = threadIdx.x;

    const float* roi = rois + (size_t)r * 5;
    const int b = (int)roi[0];
    int x0 = (int)rintf(roi[1] * 0.03125f);
    int y0 = (int)rintf(roi[2] * 0.03125f);
    int x1 = (int)rintf(roi[3] * 0.03125f);
    int y1 = (int)rintf(roi[4] * 0.03125f);
    x0 = min(max(x0, 0), W - 1);
    y0 = min(max(y0, 0), H - 1);
    x1 = min(max(x1, 0), W - 1);
    y1 = min(max(y1, 0), H - 1);

    float* o = out + (((size_t)r * C + c4 * 4) * P + i) * P + j;
    if (!((x0 < x1) && (y0 < y1))) {
        o[0] = 0.0f; o[PP] = 0.0f; o[2 * PP] = 0.0f; o[3 * PP] = 0.0f;
        return;
    }
    const int Lh = x1 - x0, Lw = y1 - y0;
    const int hs = x0 + (i * Lh) / P;
    const int he = x0 + ((i + 1) * Lh + (P - 1)) / P;
    const int ws = y0 + (j * Lw) / P;
    const int we = y0 + ((j + 1) * Lw + (P - 1)) / P;
    const int bh = he - hs, bw = we - ws;
    const float* base = ft + (((size_t)b * H + hs) * W + ws) * C + c4 * 4;
    float mx = -INFINITY, my = -INFINITY, mz = -INFINITY, mw = -INFINITY;
    for (int h = 0; h < bh; h += 2) {
        const int h2 = min(h + 1, bh - 1);
        const float* r0 = base + (size_t)h  * (W * C);
        const float* r1 = base + (size_t)h2 * (W * C);
        for (int w = 0; w < bw; w += 2) {
            const int w2 = min(w + 1, bw - 1);
            const float4 a  = *(const float4*)(r0 + (size_t)w  * C);
            const float4 bb = *(const float4*)(r0 + (size_t)w2 * C);
            const float4 cc = *(const float4*)(r1 + (size_t)w  * C);
            const float4 dd = *(const float4*)(r1 + (size_t)w2 * C);
            mx = fmaxf(fmaxf(fmaxf(mx, a.x), fmaxf(bb.x, cc.x)), dd.x);
            my = fmaxf(fmaxf(fmaxf(my, a.y), fmaxf(bb.y, cc.y)), dd.y);
            mz = fmaxf(fmaxf(fmaxf(mz, a.z), fmaxf(bb.z, cc.z)), dd.z);
            mw = fmaxf(fmaxf(fmaxf(mw, a.w), fmaxf(bb.w, cc.w)), dd.w);
        }
    }
    o[0] = mx; o[PP] = my; o[2 * PP] = mz; o[3 * PP] = mw;
}

// ---------------------------------------------------------------------------
// Fallback tier 2: no workspace
// ---------------------------------------------------------------------------
__global__ __launch_bounds__(256) void roi_pool_naive_kernel(
    const float* __restrict__ features, const float* __restrict__ rois,
    float* __restrict__ out)
{
    const int rb = blockIdx.x;
    const int r = rb / P;
    const int i = rb % P;
    const int c = threadIdx.x;

    const float* roi = rois + (size_t)r * 5;
    const int b = (int)roi[0];
    int x0 = (int)rintf(roi[1] * 0.03125f);
    int y0 = (int)rintf(roi[2] * 0.03125f);
    int x1 = (int)rintf(roi[3] * 0.03125f);
    int y1 = (int)rintf(roi[4] * 0.03125f);
    x0 = min(max(x0, 0), W - 1);
    y0 = min(max(y0, 0), H - 1);
    x1 = min(max(x1, 0), W - 1);
    y1 = min(max(y1, 0), H - 1);

    const bool valid = (x0 < x1) && (y0 < y1);
    float* o = out + (((size_t)r * C + c) * P + i) * P;
    if (!valid) {
        #pragma unroll
        for (int j = 0; j < P; ++j) o[j] = 0.0f;
        return;
    }
    const int Lh = x1 - x0, Lw = y1 - y0;
    const int hs = x0 + (i * Lh) / P;
    const int he = x0 + ((i + 1) * Lh + (P - 1)) / P;
    int ws_[P], we_[P];
    #pragma unroll
    for (int j = 0; j < P; ++j) {
        ws_[j] = y0 + (j * Lw) / P;
        we_[j] = y0 + ((j + 1) * Lw + (P - 1)) / P;
    }
    float acc[P];
    #pragma unroll
    for (int j = 0; j < P; ++j) acc[j] = -INFINITY;
    const float* f = features + (((size_t)b * C + c) * H) * W;
    for (int h = hs; h < he; ++h) {
        const float* row = f + h * W;
        #pragma unroll
        for (int j = 0; j < P; ++j) {
            float m = acc[j];
            for (int w = ws_[j]; w < we_[j]; ++w) m = fmaxf(m, row[w]);
            acc[j] = m;
        }
    }
    #pragma unroll
    for (int j = 0; j < P; ++j) o[j] = acc[j];
}

extern "C" void kernel_launch(void* const* d_in, const int* in_sizes, int n_in,
                              void* d_out, int out_size, void* d_ws, size_t ws_size,
                              hipStream_t stream)
{
    const float* features = (const float*)d_in[0];
    const float* rois     = (const float*)d_in[1];
    float* out = (float*)d_out;

    const int R = in_sizes[1] / 5;                  // 256
    const int N = in_sizes[0] / (C * S);            // 4

    const size_t ft_bytes   = (size_t)N * C * S * sizeof(float);   // 16 MB
    const size_t ws2_bytes  = (size_t)R * PP * C * sizeof(float);  // 12.8 MB
    const size_t perm_bytes = (size_t)R * sizeof(int);
    const size_t full_need  = ft_bytes + ws2_bytes + perm_bytes;

    if (ws_size >= full_need && R <= R_MAX) {
        float* ft  = (float*)d_ws;
        float* ws2 = (float*)((char*)d_ws + ft_bytes);
        int*  perm = (int*)((char*)d_ws + ft_bytes + ws2_bytes);

        dim3 tgrid(S / TT, C / TT, N);              // 64 x 4 x 4 = 1024 blocks
        transpose_bucket_kernel<<<tgrid, 256, 0, stream>>>(features, ft, rois, perm, R);
        roi_pool_cell_kernel<<<R * NCP, 128, 0, stream>>>(ft, rois, perm, ws2);
        reorder_kernel<<<R * 2, 256, 0, stream>>>(ws2, perm, out);
    } else if (ws_size >= ft_bytes) {
        float* ft = (float*)d_ws;
        dim3 tgrid(S / TT, C / TT, N);
        transpose_bucket_kernel<<<tgrid, 256, 0, stream>>>(features, ft, rois, (int*)nullptr, 0);
        roi_pool_cell_direct_kernel<<<R * PP, 64, 0, stream>>>(ft, rois, out);
    } else {
        roi_pool_naive_kernel<<<R * P, C, 0, stream>>>(features, rois, out);
    }
}